// Round 11
// baseline (108.914 us; speedup 1.0000x reference)
//
#include <hip/hip_runtime.h>
#include <stdint.h>

// LIF neuron scan: B=16, S=2048, D=1024, fp32. NUMERICS FROZEN (absmax 0.0):
// XLA-contracted fp32 — __builtin_fmaf at syn/mem/tha sites, contract(off)
// elsewhere; selects value-identical to mul-by-{0,1}; refractory as bools
// (nref = !(fired|f1) == refr<=0; final refr = f1?2:(f2?1:0)). Step = R9 form.
//
// R10 post-mortem: +6 VALU/step of speculation REGRESSED (80.5->85us) ->
// consumer is issue-bound; only independent work can fill dep gaps.
// R11: 2 chains/lane (adjacent d pair), 128 blocks x 128 threads:
//   - per double-step: 1 ds_read_b64 (x pair), 2x lean step, 1 dwordx2 store
//     -> memory instr count per chain-step HALVES; two chains hide each
//     other's dep latency; ~30 cy/chain-step target.
//   - consumer stores directly (no loads -> no vmcnt waits ever; store
//     retire 10 B/cy/CU > issue 7 B/cy). sbuf/ds_write/helper-stores deleted.
//   - helper wave: x DMA only (32 global_load_lds per 64t x 128d tile,
//     vmcnt(0), barrier). Triple-buffered xbuf, prefetch distance 2.

#define SB 16
#define SS 2048
#define SD 1024
#define TILE 64
#define NT (SS / TILE)   // 32 tiles

typedef const __attribute__((address_space(1))) void* gas_ptr;
typedef __attribute__((address_space(3))) void* las_ptr;

struct Chain {
    float mem, syn, tha;
    bool  nref, f1, f2;
    float scale, lth;
};

__global__ __launch_bounds__(128, 1) void lif_kernel(
    const float* __restrict__ x,
    const float* __restrict__ beta_mem_p,
    const float* __restrict__ beta_syn_p,
    const float* __restrict__ adapt_p,
    const float* __restrict__ scale_p,
    const float* __restrict__ lth_p,
    float* __restrict__ out)
{
#pragma clang fp contract(off)
    __shared__ __attribute__((aligned(16))) float xbuf[3][TILE][128];  // 96 KB

    const int bk = blockIdx.x;           // 0..127
    const int b  = bk >> 3;              // batch 0..15
    const int d0 = (bk & 7) << 7;        // first of this block's 128 d's

    if (threadIdx.x < 64) {
        // ============ consumer wave: 2 chains per lane ============
        const int lane = threadIdx.x;
        const int dA   = d0 + 2 * lane;      // chain 0
        const int dB   = dA + 1;             // chain 1

        const float beta_mem = beta_mem_p[0];
        const float beta_syn = beta_syn_p[0];
        const float p        = adapt_p[0];

        Chain c0{0.f, 0.f, 0.f, true, false, false, scale_p[dA], lth_p[dA]};
        Chain c1{0.f, 0.f, 0.f, true, false, false, scale_p[dB], lth_p[dB]};

        // spike store: float2 per double-step, coalesced 512B/wave
        float2* out2 = (float2*)(out + ((size_t)b * SS) * SD + d0);
        int sidx = lane;                     // float2 index; += SD/2 per step

        // FROZEN numerics (R9 lean form, verified absmax 0.0)
        auto step = [&](float xt, Chain& c) -> float {
            c.syn = __builtin_fmaf(beta_syn, c.syn, xt);
            const float syn_eff = c.nref ? c.syn : 0.f;          // syn*nonref
            c.mem = __builtin_fmaf(beta_mem, c.mem, syn_eff);
            const float q      = p * c.tha;
            const float cur_th = __builtin_fmaf(q, c.scale, c.lth);
            const bool  fired  = (c.mem >= cur_th);
            const float spike  = fired ? 1.f : 0.f;
            c.mem = c.mem - (fired ? cur_th : 0.f);              // -spike*cur_th
            c.tha = __builtin_fmaf(0.9f, c.tha, fired ? 0.1f : 0.f);
            c.nref = !(fired || c.f1);
            c.f2 = c.f1; c.f1 = fired;
            return spike;
        };

        __syncthreads();                     // tiles 0,1 staged

        int cbuf = 0;
        for (int k = 0; k < NT; ++k) {
            // x pairs for this tile, group-read 16 timesteps at a time
            float2 xa[16];
            #pragma unroll
            for (int g = 0; g < 4; ++g) {
                #pragma unroll
                for (int i = 0; i < 16; ++i)
                    xa[i] = *(const float2*)&xbuf[cbuf][g * 16 + i][2 * lane];
                #pragma unroll
                for (int i = 0; i < 16; ++i) {
                    float2 sv;
                    sv.x = step(xa[i].x, c0);
                    sv.y = step(xa[i].y, c1);
                    out2[sidx] = sv;
                    sidx += SD / 2;
                }
            }
            __syncthreads();                 // next tile staged
            cbuf = (cbuf == 2) ? 0 : cbuf + 1;
        }

        // final carry: membrane, synaptic, th_adapt, refractory (each B x D)
        const float r0 = c0.f1 ? 2.0f : (c0.f2 ? 1.0f : 0.0f);
        const float r1 = c1.f1 ? 2.0f : (c1.f2 ? 1.0f : 0.0f);
        const size_t base = (size_t)SB * SS * SD;
        const size_t row  = (size_t)b * SD + d0;
        float2* m2 = (float2*)(out + base + 0 * (size_t)SB * SD + row);
        float2* s2 = (float2*)(out + base + 1 * (size_t)SB * SD + row);
        float2* t2 = (float2*)(out + base + 2 * (size_t)SB * SD + row);
        float2* r2 = (float2*)(out + base + 3 * (size_t)SB * SD + row);
        m2[lane] = make_float2(c0.mem, c1.mem);
        s2[lane] = make_float2(c0.syn, c1.syn);
        t2[lane] = make_float2(c0.tha, c1.tha);
        r2[lane] = make_float2(r0, r1);
    } else {
        // ============ helper wave: x DMA only ============
        const int hl = threadIdx.x - 64;     // 0..63

        // call r stages t-rows 2r,2r+1 of the 64t x 128d tile:
        // lane hl -> t-row 2r+(hl>>5), dloc (hl&31)*4; LDS dest linear.
        const int trow = hl >> 5;            // 0..1
        const int dcol = (hl & 31) << 2;     // 0,4,...,124
        const float* src_base =
            x + ((size_t)b * SS) * SD + d0 + (size_t)trow * SD + dcol;

        auto issue_tile = [&](int k, int buf) {
            const float* s0 = src_base + (size_t)(k * TILE) * SD;
            float* dst = &xbuf[buf][0][0];
            #pragma unroll
            for (int r = 0; r < 32; ++r) {
                __builtin_amdgcn_global_load_lds(
                    (gas_ptr)(s0 + (size_t)(2 * r) * SD),
                    (las_ptr)(dst + r * 2 * 128),
                    16, 0, 0);
            }
        };

        issue_tile(0, 0);
        issue_tile(1, 1);
        asm volatile("s_waitcnt vmcnt(0)" ::: "memory");
        __syncthreads();                     // tiles 0,1 landed

        int nbuf = 2;
        for (int k = 0; k < NT; ++k) {
            if (k + 2 < NT) {
                issue_tile(k + 2, nbuf);     // buf was read in iter k-1
                nbuf = (nbuf == 2) ? 0 : nbuf + 1;
                asm volatile("s_waitcnt vmcnt(0)" ::: "memory");
            }
            __syncthreads();                 // DMA k+2 landed before iter k+2
        }
    }
}

extern "C" void kernel_launch(void* const* d_in, const int* in_sizes, int n_in,
                              void* d_out, int out_size, void* d_ws, size_t ws_size,
                              hipStream_t stream) {
    const float* x        = (const float*)d_in[0];
    const float* beta_mem = (const float*)d_in[1];
    const float* beta_syn = (const float*)d_in[2];
    const float* adapt_p  = (const float*)d_in[3];
    const float* scale    = (const float*)d_in[4];
    const float* lth      = (const float*)d_in[5];
    float* out = (float*)d_out;

    // 128 blocks x 128 threads: consumer (2 chains/lane) + helper (DMA)
    lif_kernel<<<128, 128, 0, stream>>>(x, beta_mem, beta_syn, adapt_p, scale, lth, out);
}

// Round 12
// 77.640 us; speedup vs baseline: 1.4028x; 1.4028x over previous
//
#include <hip/hip_runtime.h>
#include <stdint.h>

// LIF neuron scan: B=16, S=2048, D=1024, fp32. NUMERICS FROZEN (absmax 0.0):
// XLA-contracted fp32 — __builtin_fmaf at syn/mem/tha sites, contract(off)
// elsewhere. Value-identical algebra used here:
//   - mem reset: fmaf(-spike, cur_th, memf) == memf - spike*cur_th exactly
//     (spike in {0,1} -> product exact -> one rounding either way).
//   - tha: fmaf(0.9f, tha, 0.1f*spike), 0.1f*spike exact.
//   - syn_eff = nref ? syn : 0  (mask select, == syn*nonref).
//   - refractory as bools: nref=!(fired|f1); final refr=f1?2:(f2?1:0).
//
// R10/R11 post-mortem: speculation (+issue) and 2-chains/lane (-CUs) both
// regressed -> serial core is in-order issue + chain + VCC hazards. R12 =
// R9 structure (helper wave owns ALL vmem; consumer pure compute) with the
// step trimmed to 10 VALU and 2 fewer VCC-read hazards.

#define SB 16
#define SS 2048
#define SD 1024
#define TILE 64
#define NT (SS / TILE)   // 32 tiles

typedef const __attribute__((address_space(1))) void* gas_ptr;
typedef __attribute__((address_space(3))) void* las_ptr;

__global__ __launch_bounds__(128, 1) void lif_kernel(
    const float* __restrict__ x,
    const float* __restrict__ beta_mem_p,
    const float* __restrict__ beta_syn_p,
    const float* __restrict__ adapt_p,
    const float* __restrict__ scale_p,
    const float* __restrict__ lth_p,
    float* __restrict__ out)
{
#pragma clang fp contract(off)
    __shared__ __attribute__((aligned(16))) float xbuf[3][TILE][64];  // 48 KB
    __shared__ float sbuf[2][64][TILE + 1];                           // 33 KB

    const int bk = blockIdx.x;           // 0..255
    const int b  = bk >> 4;              // batch
    const int d0 = (bk & 15) << 6;       // first of this block's 64 d's

    if (threadIdx.x < 64) {
        // ================= consumer wave: pure compute =================
        const int lane = threadIdx.x;
        const int d    = d0 + lane;

        const float beta_mem = beta_mem_p[0];
        const float beta_syn = beta_syn_p[0];
        const float p        = adapt_p[0];
        const float scale    = scale_p[d];
        const float lth      = lth_p[d];

        float mem = 0.f, syn = 0.f, tha = 0.f;
        bool  nref = true;                 // refr<=0 at t=0
        bool  f1 = false, f2 = false;      // fired at t-1 / t-2

        __syncthreads();                   // tile 0 staged (helper prologue)

        int cbuf = 0;
        for (int k = 0; k < NT; ++k) {
            const int sb = k & 1;

            // whole 64-step x-tile into registers (static indexing)
            float xa[16], xbv[16], xc[16], xd[16];
            #pragma unroll
            for (int i = 0; i < 16; ++i) xa[i]  = xbuf[cbuf][i][lane];
            #pragma unroll
            for (int i = 0; i < 16; ++i) xbv[i] = xbuf[cbuf][16 + i][lane];
            #pragma unroll
            for (int i = 0; i < 16; ++i) xc[i]  = xbuf[cbuf][32 + i][lane];
            #pragma unroll
            for (int i = 0; i < 16; ++i) xd[i]  = xbuf[cbuf][48 + i][lane];

            // FROZEN numerics, hazard-trimmed form (see header proofs)
            auto step = [&](float xt, int ti) {
                syn = __builtin_fmaf(beta_syn, syn, xt);
                const float syn_eff = nref ? syn : 0.f;        // syn*nonref
                const float memf = __builtin_fmaf(beta_mem, mem, syn_eff);
                const float q      = p * tha;
                const float cur_th = __builtin_fmaf(q, scale, lth);
                const bool  fired  = (memf >= cur_th);
                const float spike  = fired ? 1.f : 0.f;
                mem = __builtin_fmaf(-spike, cur_th, memf);    // == memf-spk*cth
                tha = __builtin_fmaf(0.9f, tha, 0.1f * spike); // exact product
                nref = !(fired || f1);
                f2 = f1; f1 = fired;
                sbuf[sb][lane][ti] = spike;
            };

            #pragma unroll
            for (int i = 0; i < 16; ++i) step(xa[i], i);
            #pragma unroll
            for (int i = 0; i < 16; ++i) step(xbv[i], 16 + i);
            #pragma unroll
            for (int i = 0; i < 16; ++i) step(xc[i], 32 + i);
            #pragma unroll
            for (int i = 0; i < 16; ++i) step(xd[i], 48 + i);

            __syncthreads();               // spikes visible; next x staged
            cbuf = (cbuf == 2) ? 0 : cbuf + 1;
        }

        // final carry: membrane, synaptic, th_adapt, refractory (each B x D)
        const float refr = f1 ? 2.0f : (f2 ? 1.0f : 0.0f);
        const size_t base = (size_t)SB * SS * SD;
        const size_t off  = (size_t)b * SD + d;
        out[base + 0 * (size_t)SB * SD + off] = mem;
        out[base + 1 * (size_t)SB * SD + off] = syn;
        out[base + 2 * (size_t)SB * SD + off] = tha;
        out[base + 3 * (size_t)SB * SD + off] = refr;
    } else {
        // ================= helper wave: all vmem =================
        const int hl = threadIdx.x - 64;   // 0..63

        const float* xb   = x   + ((size_t)b * SS) * SD + d0;
        float*       outb = out + ((size_t)b * SS) * SD + d0;  // uniform base

        // DMA map: call r stages rows 4r..4r+3; lane hl -> row 4r+(hl>>4),
        // cols ((hl&15)*4..+3); LDS dest = uniform base + hl*16 (linear).
        const int srow = hl >> 4;
        const int scol = (hl & 15) << 2;
        const float* src_base = xb + (size_t)srow * SD + scol;

        auto issue_tile = [&](int k, int buf) {
            const float* s0 = src_base + (size_t)(k * TILE) * SD;
            float* dst = &xbuf[buf][0][0];
            #pragma unroll
            for (int r = 0; r < 16; ++r) {
                __builtin_amdgcn_global_load_lds(
                    (gas_ptr)(s0 + (size_t)(r * 4) * SD),
                    (las_ptr)(dst + r * 4 * 64),
                    16, 0, 0);
            }
        };

        auto store_tile = [&](int tk) {    // spikes of tile tk -> global
            const int sb = tk & 1;
            int idx = tk * TILE * SD + hl; // 32-bit index from uniform base
            #pragma unroll 8
            for (int t = 0; t < TILE; ++t) {
                outb[idx] = sbuf[sb][hl][t];
                idx += SD;
            }
        };

        issue_tile(0, 0);
        issue_tile(1, 1);
        __syncthreads();                   // vmcnt(0): tiles 0,1 landed

        int nbuf = 2;
        for (int k = 0; k < NT; ++k) {
            if (k + 2 < NT) {
                issue_tile(k + 2, nbuf);   // overwrites buf read in iter k-1
                nbuf = (nbuf == 2) ? 0 : nbuf + 1;
            }
            if (k >= 1) store_tile(k - 1);
            __syncthreads();               // vmcnt(0): DMA k+1 landed
        }
        store_tile(NT - 1);
    }
}

extern "C" void kernel_launch(void* const* d_in, const int* in_sizes, int n_in,
                              void* d_out, int out_size, void* d_ws, size_t ws_size,
                              hipStream_t stream) {
    const float* x        = (const float*)d_in[0];
    const float* beta_mem = (const float*)d_in[1];
    const float* beta_syn = (const float*)d_in[2];
    const float* adapt_p  = (const float*)d_in[3];
    const float* scale    = (const float*)d_in[4];
    const float* lth      = (const float*)d_in[5];
    float* out = (float*)d_out;

    // 256 blocks x 128 threads: consumer wave + helper wave per block
    lif_kernel<<<256, 128, 0, stream>>>(x, beta_mem, beta_syn, adapt_p, scale, lth, out);
}

// Round 13
// 76.918 us; speedup vs baseline: 1.4160x; 1.0094x over previous
//
#include <hip/hip_runtime.h>
#include <stdint.h>

// LIF neuron scan: B=16, S=2048, D=1024, fp32. NUMERICS FROZEN (absmax 0.0):
// XLA-contracted fp32 — __builtin_fmaf at syn/mem/tha sites, contract(off)
// elsewhere. Value-identical algebra (verified):
//   - mem reset: fmaf(-spike, cur_th, memf) == memf - spike*cur_th exactly.
//   - tha: fmaf(0.9f, tha, 0.1f*spike), 0.1f*spike exact.
//   - syn_eff = nref ? syn : 0 (mask select == syn*nonref).
//   - refractory as bools: nref=!(fired|f1); final refr=f1?2:(f2?1:0).
//
// R12 post-mortem: 77.6us; removing 2 VALU+2 hazards bought 3.4 cy/step ->
// consumer pinned by in-order issue+chain+hazards; TLP can't help (serial t).
// R13: offload the spike-INDEPENDENT syn recurrence to the helper wave
// (proven ~4x slack). syn_t = fmaf(beta_syn, syn_{t-1}, x_t) computed one
// tile ahead on the helper, staged via synbuf; identical op order -> bit-
// identical values. Consumer step: 9 VALU + 1 ds_write; x never touches
// the consumer.
//   iter k: consumer: consume synbuf[k&1], spikes -> sbuf[k&1].
//           helper:  syn tile k+1 (from xbuf[(k+1)&1]) -> synbuf[(k+1)&1];
//                    DMA x tile k+2 -> xbuf[k&1] (same-wave WAR-safe);
//                    store spikes k-1; barrier (drains its vmcnt).

#define SB 16
#define SS 2048
#define SD 1024
#define TILE 64
#define NT (SS / TILE)   // 32 tiles

typedef const __attribute__((address_space(1))) void* gas_ptr;
typedef __attribute__((address_space(3))) void* las_ptr;

__global__ __launch_bounds__(128, 1) void lif_kernel(
    const float* __restrict__ x,
    const float* __restrict__ beta_mem_p,
    const float* __restrict__ beta_syn_p,
    const float* __restrict__ adapt_p,
    const float* __restrict__ scale_p,
    const float* __restrict__ lth_p,
    float* __restrict__ out)
{
#pragma clang fp contract(off)
    __shared__ __attribute__((aligned(16))) float xbuf[2][TILE][64];   // 32 KB
    __shared__ __attribute__((aligned(16))) float synbuf[2][TILE][64]; // 32 KB
    __shared__ float sbuf[2][64][TILE + 1];                            // 33 KB

    const int bk = blockIdx.x;           // 0..255
    const int b  = bk >> 4;              // batch
    const int d0 = (bk & 15) << 6;       // first of this block's 64 d's

    if (threadIdx.x < 64) {
        // ========== consumer wave: spike recurrence only ==========
        const int lane = threadIdx.x;
        const int d    = d0 + lane;

        const float beta_mem = beta_mem_p[0];
        const float p        = adapt_p[0];
        const float scale    = scale_p[d];
        const float lth      = lth_p[d];

        float mem = 0.f, tha = 0.f;
        bool  nref = true;                 // refr<=0 at t=0
        bool  f1 = false, f2 = false;      // fired at t-1 / t-2

        __syncthreads();                   // A: x tiles 0,1 landed
        __syncthreads();                   // B: synbuf[0] ready

        for (int k = 0; k < NT; ++k) {
            const int sb = k & 1;

            // whole 64-step syn-tile into registers (static indexing)
            float sa[16], sbv[16], sc[16], sd_[16];
            #pragma unroll
            for (int i = 0; i < 16; ++i) sa[i]  = synbuf[sb][i][lane];
            #pragma unroll
            for (int i = 0; i < 16; ++i) sbv[i] = synbuf[sb][16 + i][lane];
            #pragma unroll
            for (int i = 0; i < 16; ++i) sc[i]  = synbuf[sb][32 + i][lane];
            #pragma unroll
            for (int i = 0; i < 16; ++i) sd_[i] = synbuf[sb][48 + i][lane];

            // FROZEN numerics, syn-free hazard-trimmed form
            auto step = [&](float sv, int ti) {
                const float syn_eff = nref ? sv : 0.f;         // syn*nonref
                const float memf = __builtin_fmaf(beta_mem, mem, syn_eff);
                const float q      = p * tha;
                const float cur_th = __builtin_fmaf(q, scale, lth);
                const bool  fired  = (memf >= cur_th);
                const float spike  = fired ? 1.f : 0.f;
                mem = __builtin_fmaf(-spike, cur_th, memf);    // == memf-spk*cth
                tha = __builtin_fmaf(0.9f, tha, 0.1f * spike); // exact product
                nref = !(fired || f1);
                f2 = f1; f1 = fired;
                sbuf[sb][lane][ti] = spike;
            };

            #pragma unroll
            for (int i = 0; i < 16; ++i) step(sa[i], i);
            #pragma unroll
            for (int i = 0; i < 16; ++i) step(sbv[i], 16 + i);
            #pragma unroll
            for (int i = 0; i < 16; ++i) step(sc[i], 32 + i);
            #pragma unroll
            for (int i = 0; i < 16; ++i) step(sd_[i], 48 + i);

            __syncthreads();               // spikes visible; next syn staged
        }

        // final carry: membrane, th_adapt, refractory (helper writes syn)
        const float refr = f1 ? 2.0f : (f2 ? 1.0f : 0.0f);
        const size_t base = (size_t)SB * SS * SD;
        const size_t off  = (size_t)b * SD + d;
        out[base + 0 * (size_t)SB * SD + off] = mem;
        out[base + 2 * (size_t)SB * SD + off] = tha;
        out[base + 3 * (size_t)SB * SD + off] = refr;
    } else {
        // ========== helper wave: all vmem + syn recurrence ==========
        const int hl = threadIdx.x - 64;   // 0..63

        const float beta_syn = beta_syn_p[0];
        const float* xb   = x   + ((size_t)b * SS) * SD + d0;
        float*       outb = out + ((size_t)b * SS) * SD + d0;  // uniform base

        // DMA map: call r stages rows 4r..4r+3; lane hl -> row 4r+(hl>>4),
        // cols ((hl&15)*4..+3); LDS dest = uniform base + hl*16 (linear).
        const int srow = hl >> 4;
        const int scol = (hl & 15) << 2;
        const float* src_base = xb + (size_t)srow * SD + scol;

        auto issue_tile = [&](int k, int buf) {
            const float* s0 = src_base + (size_t)(k * TILE) * SD;
            float* dst = &xbuf[buf][0][0];
            #pragma unroll
            for (int r = 0; r < 16; ++r) {
                __builtin_amdgcn_global_load_lds(
                    (gas_ptr)(s0 + (size_t)(r * 4) * SD),
                    (las_ptr)(dst + r * 4 * 64),
                    16, 0, 0);
            }
        };

        float hsyn = 0.f;                  // syn carry (d = d0+hl)
        auto syn_tile = [&](int k) {       // syn for tile k -> synbuf[k&1]
            const int xs = k & 1;
            #pragma unroll
            for (int g = 0; g < 4; ++g) {
                float xv[16];
                #pragma unroll
                for (int i = 0; i < 16; ++i) xv[i] = xbuf[xs][g * 16 + i][hl];
                #pragma unroll
                for (int i = 0; i < 16; ++i) {
                    hsyn = __builtin_fmaf(beta_syn, hsyn, xv[i]);  // FROZEN op
                    synbuf[xs][g * 16 + i][hl] = hsyn;
                }
            }
        };

        auto store_tile = [&](int tk) {    // spikes of tile tk -> global
            const int sb = tk & 1;
            int idx = tk * TILE * SD + hl; // 32-bit index from uniform base
            #pragma unroll 8
            for (int t = 0; t < TILE; ++t) {
                outb[idx] = sbuf[sb][hl][t];
                idx += SD;
            }
        };

        issue_tile(0, 0);
        issue_tile(1, 1);
        __syncthreads();                   // A: vmcnt(0) -> tiles 0,1 landed
        syn_tile(0);
        __syncthreads();                   // B: synbuf[0] visible

        for (int k = 0; k < NT; ++k) {
            if (k + 1 < NT) syn_tile(k + 1);        // reads xbuf[(k+1)&1]
            if (k + 2 < NT) issue_tile(k + 2, k & 1); // WAR-safe (same wave)
            if (k >= 1) store_tile(k - 1);
            __syncthreads();               // drains vmcnt: DMA k+2 landed
        }
        store_tile(NT - 1);

        // final syn carry (B x D row of this block)
        const size_t base = (size_t)SB * SS * SD;
        out[base + 1 * (size_t)SB * SD + (size_t)b * SD + d0 + hl] = hsyn;
    }
}

extern "C" void kernel_launch(void* const* d_in, const int* in_sizes, int n_in,
                              void* d_out, int out_size, void* d_ws, size_t ws_size,
                              hipStream_t stream) {
    const float* x        = (const float*)d_in[0];
    const float* beta_mem = (const float*)d_in[1];
    const float* beta_syn = (const float*)d_in[2];
    const float* adapt_p  = (const float*)d_in[3];
    const float* scale    = (const float*)d_in[4];
    const float* lth      = (const float*)d_in[5];
    float* out = (float*)d_out;

    // 256 blocks x 128 threads: consumer wave + helper wave per block
    lif_kernel<<<256, 128, 0, stream>>>(x, beta_mem, beta_syn, adapt_p, scale, lth, out);
}